// Round 7
// baseline (105.991 us; speedup 1.0000x reference)
//
#include <hip/hip_runtime.h>
#include <hip/hip_bf16.h>

#define N_NODES 100000
#define N_EDGES 1250000
#define DIM 64
#define NB 782            // ceil(100000/128) buckets of 128 nodes
#define NSEG (NB * 8)     // per-(bucket, xcd-slot) segments
#define NCHUNK 512
#define CHUNK 2442        // ceil(1250000/512)
#define MAXE 4096         // per-round LDS edge capacity in fused gather

typedef __attribute__((ext_vector_type(8))) short short8;
typedef __attribute__((ext_vector_type(8))) __bf16 bf16x8;
typedef __attribute__((ext_vector_type(4))) float f32x4;

static __device__ __forceinline__ short f2bf(float f) {
    union { float f; unsigned u; } v; v.f = f;
    unsigned r = (v.u + 0x7fffu + ((v.u >> 16) & 1u)) >> 16;
    return (short)r;
}
static __device__ __forceinline__ float bfu2f(unsigned u) {
    union { unsigned u; float f; } v; v.u = u << 16; return v.f;
}

// ---------------- prologue: conv_feat + prep_w + segmented bucket counts ----------------
__global__ __launch_bounds__(256) void prologue(const float* __restrict__ feat,
                                                short* __restrict__ featbf,
                                                const float* __restrict__ W1,
                                                const float* __restrict__ W2,
                                                short* __restrict__ wf,
                                                const int* __restrict__ dst,
                                                int* __restrict__ btot8,
                                                int basePrep, int baseCnt) {
    __shared__ int scnt[NB];
    int blk = blockIdx.x;
    if (blk < basePrep) {
        int i = (blk * 256 + threadIdx.x) * 8;
        float4 a = *(const float4*)(feat + i);
        float4 b = *(const float4*)(feat + i + 4);
        short8 t;
        t[0] = f2bf(a.x); t[1] = f2bf(a.y); t[2] = f2bf(a.z); t[3] = f2bf(a.w);
        t[4] = f2bf(b.x); t[5] = f2bf(b.y); t[6] = f2bf(b.z); t[7] = f2bf(b.w);
        *(short8*)(featbf + i) = t;
    } else if (blk < baseCnt) {
        int idx = (blk - basePrep) * 256 + threadIdx.x;   // 0..8191
        int layer = idx >> 12;
        int fi = idx & 4095;
        int fragidx = fi >> 9;
        int lane = (fi >> 3) & 63;
        int jj = fi & 7;
        int ct = fragidx >> 1, kt = fragidx & 1;
        int k = kt * 32 + (lane >> 4) * 8 + jj;
        int j = ct * 16 + (lane & 15);
        const float* W = layer ? W2 : W1;
        wf[idx] = f2bf(W[k * DIM + j]);
    } else {
        int c = blk - baseCnt;
        int x = c & 7;                  // must match partition2's slot for chunk c
        for (int b = threadIdx.x; b < NB; b += 256) scnt[b] = 0;
        __syncthreads();
        int base = c * CHUNK;
        int end = base + CHUNK; if (end > N_EDGES) end = N_EDGES;
        for (int i = base + threadIdx.x; i < end; i += 256)
            atomicAdd(&scnt[dst[i] >> 7], 1);
        __syncthreads();
        for (int b = threadIdx.x; b < NB; b += 256)
            if (scnt[b]) atomicAdd(&btot8[b * 8 + x], scnt[b]);
    }
}

// ---------------- exclusive scan of btot8[NSEG] -> bb (with sentinel), cur ----------------
__global__ __launch_bounds__(1024) void scan6k(const int* __restrict__ btot8,
                                               int* __restrict__ bb,
                                               int* __restrict__ cur) {
    __shared__ int s[1024];
    int t = threadIdx.x;
    int base = t * 7;                   // 1024*7 = 7168 >= 6256
    int v[7]; int sum = 0;
#pragma unroll
    for (int i = 0; i < 7; ++i) {
        int idx = base + i;
        int x = (idx < NSEG) ? btot8[idx] : 0;
        v[i] = x; sum += x;
    }
    s[t] = sum; __syncthreads();
    for (int off = 1; off < 1024; off <<= 1) {
        int u = (t >= off) ? s[t - off] : 0;
        __syncthreads();
        s[t] += u;
        __syncthreads();
    }
    int ex = s[t] - sum;
#pragma unroll
    for (int i = 0; i < 7; ++i) {
        int idx = base + i;
        if (idx < NSEG) { bb[idx] = ex; cur[idx] = ex; }
        ex += v[i];
    }
    if (t == 1023) bb[NSEG] = s[1023];  // sentinel = total edges
}

// ---------------- partition: LDS count, per-XCD-segment reserve, place ----------------
__global__ __launch_bounds__(256) void partition2(const int* __restrict__ src,
                                                  const int* __restrict__ dst,
                                                  int* __restrict__ cur,
                                                  int* __restrict__ edgebuf) {
    __shared__ int cnt[NB];
    __shared__ int lcur[NB];
    int c = blockIdx.x;
    int x = c & 7;                      // heuristic XCD slot (round-robin dispatch)
    int base = c * CHUNK;
    int end = base + CHUNK; if (end > N_EDGES) end = N_EDGES;

    for (int b = threadIdx.x; b < NB; b += 256) cnt[b] = 0;
    __syncthreads();
    for (int i = base + threadIdx.x; i < end; i += 256)
        atomicAdd(&cnt[dst[i] >> 7], 1);
    __syncthreads();
    for (int b = threadIdx.x; b < NB; b += 256)
        if (cnt[b]) lcur[b] = atomicAdd(&cur[b * 8 + x], cnt[b]);
    __syncthreads();
    for (int i = base + threadIdx.x; i < end; i += 256) {
        int d = dst[i];
        int b = d >> 7;
        int p = atomicAdd(&lcur[b], 1);                     // LDS return-atomic
        edgebuf[p] = src[i] | ((d & 127) << 17);
    }
}

// ---------------- fused gather + combine + 2-layer MLP ----------------
// bb is the flat (bucket,xcd) scan with sentinel: bucket b owns [bb[b*8], bb[(b+1)*8]).
template<int BF>
__global__ __launch_bounds__(512) void fused_gather_mlp(const int* __restrict__ bb,
                                                        const int* __restrict__ edgebuf,
                                                        const void* __restrict__ featp,
                                                        const float* __restrict__ feat,
                                                        const short* __restrict__ wf,
                                                        const float* __restrict__ b1,
                                                        const float* __restrict__ b2,
                                                        const float* __restrict__ epsp,
                                                        float* __restrict__ out) {
    __shared__ union {
        struct { int ew[MAXE]; int es[MAXE]; } s;   // 32 KB sort phase
        float tile[128][66];                        // 33792 B neigh tile / hbuf
    } u;
    __shared__ int cnt[128], offs[128], cur[128];

    int b = blockIdx.x;
    int node0 = b << 7;
    int eb = bb[b * 8];
    int ec = bb[(b + 1) * 8] - eb;
    int tid = threadIdx.x;
    int c = tid & 15;               // feature chunk (4 floats)
    int slot = tid >> 4;            // 0..31

    float acc[4][4];
#pragma unroll
    for (int g = 0; g < 4; ++g)
#pragma unroll
        for (int j = 0; j < 4; ++j) acc[g][j] = 0.f;

    // ---------- phase 1: bucketed gather ----------
    for (int r0 = 0; r0 < ec; r0 += MAXE) {
        int n = ec - r0; if (n > MAXE) n = MAXE;

        if (tid < 128) cnt[tid] = 0;
        __syncthreads();

        for (int i = tid; i < n; i += 512) {
            int w = edgebuf[eb + r0 + i];
            u.s.ew[i] = w;
            atomicAdd(&cnt[(w >> 17) & 127], 1);
        }
        __syncthreads();

        if (tid < 128) offs[tid] = cnt[tid];
        __syncthreads();
        for (int d = 1; d < 128; d <<= 1) {
            int v = 0;
            if (tid < 128 && tid >= d) v = offs[tid - d];
            __syncthreads();
            if (tid < 128 && tid >= d) offs[tid] += v;
            __syncthreads();
        }
        if (tid < 128) {
            int x = offs[tid] - cnt[tid];
            offs[tid] = x;
            cur[tid] = x;
        }
        __syncthreads();

        for (int i = tid; i < n; i += 512) {
            int w = u.s.ew[i];
            int p = atomicAdd(&cur[(w >> 17) & 127], 1);
            u.s.es[p] = w & 0x1FFFF;
        }
        __syncthreads();

#pragma unroll
        for (int g = 0; g < 4; ++g) {
            int ld = g * 32 + slot;
            int s0 = offs[ld], s1 = s0 + cnt[ld];
            int i = s0;
            for (; i + 1 < s1; i += 2) {
                int sa = u.s.es[i], sb = u.s.es[i + 1];
                if (BF) {
                    uint2 pa = ((const uint2*)featp)[sa * 16 + c];
                    uint2 pb = ((const uint2*)featp)[sb * 16 + c];
                    acc[g][0] += bfu2f(pa.x & 0xffffu) + bfu2f(pb.x & 0xffffu);
                    acc[g][1] += bfu2f(pa.x >> 16)     + bfu2f(pb.x >> 16);
                    acc[g][2] += bfu2f(pa.y & 0xffffu) + bfu2f(pb.y & 0xffffu);
                    acc[g][3] += bfu2f(pa.y >> 16)     + bfu2f(pb.y >> 16);
                } else {
                    float4 va = ((const float4*)featp)[sa * 16 + c];
                    float4 vb = ((const float4*)featp)[sb * 16 + c];
                    acc[g][0] += va.x + vb.x;
                    acc[g][1] += va.y + vb.y;
                    acc[g][2] += va.z + vb.z;
                    acc[g][3] += va.w + vb.w;
                }
            }
            if (i < s1) {
                int sa = u.s.es[i];
                if (BF) {
                    uint2 pa = ((const uint2*)featp)[sa * 16 + c];
                    acc[g][0] += bfu2f(pa.x & 0xffffu);
                    acc[g][1] += bfu2f(pa.x >> 16);
                    acc[g][2] += bfu2f(pa.y & 0xffffu);
                    acc[g][3] += bfu2f(pa.y >> 16);
                } else {
                    float4 va = ((const float4*)featp)[sa * 16 + c];
                    acc[g][0] += va.x; acc[g][1] += va.y;
                    acc[g][2] += va.z; acc[g][3] += va.w;
                }
            }
        }
        __syncthreads();
    }
    __syncthreads();

    // ---------- phase 2: neigh -> LDS tile (stride 66) ----------
#pragma unroll
    for (int g = 0; g < 4; ++g) {
        int ld = g * 32 + slot;
#pragma unroll
        for (int j = 0; j < 4; ++j)
            u.tile[ld][c * 4 + j] = acc[g][j];
    }
    __syncthreads();

    // ---------- phase 3: MLP, one wave per 16 rows ----------
    int wv = tid >> 6;
    int lane = tid & 63;
    int r = lane & 15, gg = lane >> 4;
    int row = wv * 16 + r;              // local row 0..127
    int node = node0 + row;
    bool valid = node < N_NODES;
    float epsv = 1.0f + epsp[0];

    const short8* w1f8 = (const short8*)(wf);
    const short8* w2f8 = (const short8*)(wf + 4096);

    short8 a[2];
    {
        const float* fp = feat + (size_t)node * 64 + gg * 8;
#pragma unroll
        for (int kt = 0; kt < 2; ++kt) {
            float f0x=0,f0y=0,f0z=0,f0w=0,f1x=0,f1y=0,f1z=0,f1w=0;
            if (valid) {
                float4 f0 = *(const float4*)(fp + kt * 32);
                float4 f1 = *(const float4*)(fp + kt * 32 + 4);
                f0x=f0.x; f0y=f0.y; f0z=f0.z; f0w=f0.w;
                f1x=f1.x; f1y=f1.y; f1z=f1.z; f1w=f1.w;
            }
            const float2* tp = (const float2*)&u.tile[row][kt * 32 + gg * 8];
            float2 n0 = tp[0], n1 = tp[1], n2 = tp[2], n3 = tp[3];
            float rs[8] = { epsv * f0x + n0.x, epsv * f0y + n0.y,
                            epsv * f0z + n1.x, epsv * f0w + n1.y,
                            epsv * f1x + n2.x, epsv * f1y + n2.y,
                            epsv * f1z + n3.x, epsv * f1w + n3.y };
            short8 t;
#pragma unroll
            for (int jj = 0; jj < 8; ++jj) t[jj] = f2bf(rs[jj]);
            a[kt] = t;
        }
    }
    __syncthreads();    // all tile reads done before hbuf overwrite

    f32x4 acc1[4];
#pragma unroll
    for (int ct = 0; ct < 4; ++ct) {
        float bv = b1[ct * 16 + r];
        f32x4 cc = { bv, bv, bv, bv };
        cc = __builtin_amdgcn_mfma_f32_16x16x32_bf16(
                __builtin_bit_cast(bf16x8, a[0]),
                __builtin_bit_cast(bf16x8, w1f8[(ct * 2 + 0) * 64 + lane]),
                cc, 0, 0, 0);
        cc = __builtin_amdgcn_mfma_f32_16x16x32_bf16(
                __builtin_bit_cast(bf16x8, a[1]),
                __builtin_bit_cast(bf16x8, w1f8[(ct * 2 + 1) * 64 + lane]),
                cc, 0, 0, 0);
        acc1[ct] = cc;
    }

    // relu + transpose h through LDS (hbuf aliases tile region; per-wave slice)
#pragma unroll
    for (int ct = 0; ct < 4; ++ct)
#pragma unroll
        for (int i = 0; i < 4; ++i)
            u.tile[wv * 16 + gg * 4 + i][ct * 16 + r] = fmaxf(acc1[ct][i], 0.0f);
    __syncthreads();

    short8 a2[2];
#pragma unroll
    for (int kt = 0; kt < 2; ++kt) {
        const float2* hp = (const float2*)&u.tile[wv * 16 + r][kt * 32 + gg * 8];
        float2 h0 = hp[0], h1 = hp[1], h2 = hp[2], h3 = hp[3];
        float hs[8] = { h0.x, h0.y, h1.x, h1.y, h2.x, h2.y, h3.x, h3.y };
        short8 t;
#pragma unroll
        for (int jj = 0; jj < 8; ++jj) t[jj] = f2bf(hs[jj]);
        a2[kt] = t;
    }

    f32x4 acc2[4];
#pragma unroll
    for (int ct = 0; ct < 4; ++ct) {
        float bv = b2[ct * 16 + r];
        f32x4 cc = { bv, bv, bv, bv };
        cc = __builtin_amdgcn_mfma_f32_16x16x32_bf16(
                __builtin_bit_cast(bf16x8, a2[0]),
                __builtin_bit_cast(bf16x8, w2f8[(ct * 2 + 0) * 64 + lane]),
                cc, 0, 0, 0);
        cc = __builtin_amdgcn_mfma_f32_16x16x32_bf16(
                __builtin_bit_cast(bf16x8, a2[1]),
                __builtin_bit_cast(bf16x8, w2f8[(ct * 2 + 1) * 64 + lane]),
                cc, 0, 0, 0);
        acc2[ct] = cc;
    }

#pragma unroll
    for (int ct = 0; ct < 4; ++ct)
#pragma unroll
        for (int i = 0; i < 4; ++i) {
            int nrow = node0 + wv * 16 + gg * 4 + i;
            if (nrow < N_NODES)
                out[(size_t)nrow * 64 + ct * 16 + r] = acc2[ct][i];
        }
}

// ---------------- tiny-ws fallback: atomic scatter + separate MLP ----------------
__global__ __launch_bounds__(256) void scatter_edges(const float4* __restrict__ feat4,
                                                     const int* __restrict__ src,
                                                     const int* __restrict__ dst,
                                                     float* __restrict__ neigh) {
    int idx = blockIdx.x * 256 + threadIdx.x;
    int e = idx >> 4, c = idx & 15;
    int s = src[e], d = dst[e];
    float4 v = feat4[s * 16 + c];
    float* p = neigh + d * 64 + c * 4;
    unsafeAtomicAdd(p + 0, v.x);
    unsafeAtomicAdd(p + 1, v.y);
    unsafeAtomicAdd(p + 2, v.z);
    unsafeAtomicAdd(p + 3, v.w);
}

__global__ __launch_bounds__(256) void prep_w(const float* __restrict__ W1,
                                              const float* __restrict__ W2,
                                              short* __restrict__ wf) {
    int idx = blockIdx.x * 256 + threadIdx.x;
    int layer = idx >> 12;
    int fi = idx & 4095;
    int fragidx = fi >> 9;
    int lane = (fi >> 3) & 63;
    int jj = fi & 7;
    int ct = fragidx >> 1, kt = fragidx & 1;
    int k = kt * 32 + (lane >> 4) * 8 + jj;
    int j = ct * 16 + (lane & 15);
    const float* W = layer ? W2 : W1;
    wf[idx] = f2bf(W[k * DIM + j]);
}

__global__ __launch_bounds__(256) void gin_mlp(const float* __restrict__ feat,
                                               float* __restrict__ neigh_out,
                                               const short* __restrict__ wf,
                                               const float* __restrict__ b1,
                                               const float* __restrict__ b2,
                                               const float* __restrict__ epsp) {
    __shared__ float hbuf[4][16][66];
    int lane = threadIdx.x & 63;
    int wv = threadIdx.x >> 6;
    int r = lane & 15, g = lane >> 4;
    int row0 = blockIdx.x * 64 + wv * 16;
    int node = row0 + r;
    bool valid = node < N_NODES;
    float epsv = 1.0f + epsp[0];
    const short8* w1f8 = (const short8*)(wf);
    const short8* w2f8 = (const short8*)(wf + 4096);
    short8 a[2];
    if (valid) {
        const float* fp = feat + node * 64 + g * 8;
        const float* np_ = neigh_out + node * 64 + g * 8;
#pragma unroll
        for (int kt = 0; kt < 2; ++kt) {
            float4 f0 = *(const float4*)(fp + kt * 32);
            float4 f1 = *(const float4*)(fp + kt * 32 + 4);
            float4 n0 = *(const float4*)(np_ + kt * 32);
            float4 n1 = *(const float4*)(np_ + kt * 32 + 4);
            float rs[8] = { epsv * f0.x + n0.x, epsv * f0.y + n0.y,
                            epsv * f0.z + n0.z, epsv * f0.w + n0.w,
                            epsv * f1.x + n1.x, epsv * f1.y + n1.y,
                            epsv * f1.z + n1.z, epsv * f1.w + n1.w };
            short8 t;
#pragma unroll
            for (int jj = 0; jj < 8; ++jj) t[jj] = f2bf(rs[jj]);
            a[kt] = t;
        }
    } else {
        short8 z = { 0,0,0,0,0,0,0,0 };
        a[0] = z; a[1] = z;
    }
    f32x4 acc[4];
#pragma unroll
    for (int ct = 0; ct < 4; ++ct) {
        float bv = b1[ct * 16 + r];
        f32x4 c = { bv, bv, bv, bv };
        c = __builtin_amdgcn_mfma_f32_16x16x32_bf16(
                __builtin_bit_cast(bf16x8, a[0]),
                __builtin_bit_cast(bf16x8, w1f8[(ct * 2 + 0) * 64 + lane]), c, 0, 0, 0);
        c = __builtin_amdgcn_mfma_f32_16x16x32_bf16(
                __builtin_bit_cast(bf16x8, a[1]),
                __builtin_bit_cast(bf16x8, w1f8[(ct * 2 + 1) * 64 + lane]), c, 0, 0, 0);
        acc[ct] = c;
    }
#pragma unroll
    for (int ct = 0; ct < 4; ++ct)
#pragma unroll
        for (int i = 0; i < 4; ++i)
            hbuf[wv][g * 4 + i][ct * 16 + r] = fmaxf(acc[ct][i], 0.0f);
    __syncthreads();
    short8 a2[2];
#pragma unroll
    for (int kt = 0; kt < 2; ++kt) {
        const float2* hp = (const float2*)&hbuf[wv][r][kt * 32 + g * 8];
        float2 h0 = hp[0], h1 = hp[1], h2 = hp[2], h3 = hp[3];
        float hs[8] = { h0.x, h0.y, h1.x, h1.y, h2.x, h2.y, h3.x, h3.y };
        short8 t;
#pragma unroll
        for (int jj = 0; jj < 8; ++jj) t[jj] = f2bf(hs[jj]);
        a2[kt] = t;
    }
    f32x4 acc2[4];
#pragma unroll
    for (int ct = 0; ct < 4; ++ct) {
        float bv = b2[ct * 16 + r];
        f32x4 c = { bv, bv, bv, bv };
        c = __builtin_amdgcn_mfma_f32_16x16x32_bf16(
                __builtin_bit_cast(bf16x8, a2[0]),
                __builtin_bit_cast(bf16x8, w2f8[(ct * 2 + 0) * 64 + lane]), c, 0, 0, 0);
        c = __builtin_amdgcn_mfma_f32_16x16x32_bf16(
                __builtin_bit_cast(bf16x8, a2[1]),
                __builtin_bit_cast(bf16x8, w2f8[(ct * 2 + 1) * 64 + lane]), c, 0, 0, 0);
        acc2[ct] = c;
    }
#pragma unroll
    for (int ct = 0; ct < 4; ++ct)
#pragma unroll
        for (int i = 0; i < 4; ++i) {
            int nrow = row0 + g * 4 + i;
            if (nrow < N_NODES)
                neigh_out[nrow * 64 + ct * 16 + r] = acc2[ct][i];
        }
}

extern "C" void kernel_launch(void* const* d_in, const int* in_sizes, int n_in,
                              void* d_out, int out_size, void* d_ws, size_t ws_size,
                              hipStream_t stream) {
    const float* feat = (const float*)d_in[0];
    const float* W1   = (const float*)d_in[1];
    const float* b1   = (const float*)d_in[2];
    const float* W2   = (const float*)d_in[3];
    const float* b2   = (const float*)d_in[4];
    const float* eps  = (const float*)d_in[5];
    const int*   src  = (const int*)d_in[6];
    const int*   dst  = (const int*)d_in[7];
    float* out = (float*)d_out;

    char* ws = (char*)d_ws;
    short* wf = (short*)ws;                                     // 16384 B

    const size_t featbf_bytes = (size_t)N_NODES * DIM * 2;      // 12.8 MB
    const size_t btot8_bytes  = (size_t)NSEG * 4;               // 25024 B
    const size_t bb_bytes     = (size_t)(NSEG + 1) * 4;         // +sentinel
    const size_t edge_bytes   = (size_t)N_EDGES * 4;            // 5 MB
    const size_t need_mid  = 16384 + btot8_bytes + bb_bytes + btot8_bytes + edge_bytes;
    const size_t need_full = need_mid + featbf_bytes;

    if (ws_size >= need_mid) {
        char* p = ws + 16384;
        short* featbf = nullptr;
        if (ws_size >= need_full) { featbf = (short*)p; p += featbf_bytes; }
        int* btot8   = (int*)p;            p += btot8_bytes;
        int* bb      = (int*)p;            p += bb_bytes;
        int* cur     = (int*)p;            p += btot8_bytes;
        int* edgebuf = (int*)p;

        hipMemsetAsync(btot8, 0, btot8_bytes, stream);

        int nConv = featbf ? 3125 : 0;          // 6.4M floats / (256*8)
        int basePrep = nConv;
        int baseCnt  = nConv + 32;              // prep_w: 8192 / 256
        prologue<<<baseCnt + NCHUNK, 256, 0, stream>>>(
            feat, featbf, W1, W2, wf, dst, btot8, basePrep, baseCnt);

        scan6k<<<1, 1024, 0, stream>>>(btot8, bb, cur);
        partition2<<<NCHUNK, 256, 0, stream>>>(src, dst, cur, edgebuf);

        if (featbf)
            fused_gather_mlp<1><<<NB, 512, 0, stream>>>(
                bb, edgebuf, featbf, feat, wf, b1, b2, eps, out);
        else
            fused_gather_mlp<0><<<NB, 512, 0, stream>>>(
                bb, edgebuf, feat, feat, wf, b1, b2, eps, out);
    } else {
        prep_w<<<32, 256, 0, stream>>>(W1, W2, wf);
        hipMemsetAsync(d_out, 0, (size_t)N_NODES * DIM * sizeof(float), stream);
        scatter_edges<<<(N_EDGES * 16) / 256, 256, 0, stream>>>(
            (const float4*)feat, src, dst, out);
        gin_mlp<<<(N_NODES + 63) / 64, 256, 0, stream>>>(feat, out, wf, b1, b2, eps);
    }
}

// Round 8
// 63.161 us; speedup vs baseline: 1.6781x; 1.6781x over previous
//
#include <hip/hip_runtime.h>
#include <hip/hip_bf16.h>

#define N_NODES 100000
#define N_EDGES 1250000
#define DIM 64
#define NB 782            // ceil(100000/128) buckets of 128 nodes
#define NCHUNK 512
#define CHUNK 2442        // ceil(1250000/512); MUST be <= MAXE
#define MAXE 4096         // per-round LDS edge capacity in fused gather

typedef __attribute__((ext_vector_type(8))) short short8;
typedef __attribute__((ext_vector_type(8))) __bf16 bf16x8;
typedef __attribute__((ext_vector_type(4))) float f32x4;

static __device__ __forceinline__ short f2bf(float f) {
    union { float f; unsigned u; } v; v.f = f;
    unsigned r = (v.u + 0x7fffu + ((v.u >> 16) & 1u)) >> 16;
    return (short)r;
}
static __device__ __forceinline__ float bfu2f(unsigned u) {
    union { unsigned u; float f; } v; v.u = u << 16; return v.f;
}

// ---------------- prologue: conv_feat + prep_w (no counting anymore) ----------------
__global__ __launch_bounds__(256) void prologue(const float* __restrict__ feat,
                                                short* __restrict__ featbf,
                                                const float* __restrict__ W1,
                                                const float* __restrict__ W2,
                                                short* __restrict__ wf,
                                                int basePrep) {
    int blk = blockIdx.x;
    if (blk < basePrep) {
        int i = (blk * 256 + threadIdx.x) * 8;
        float4 a = *(const float4*)(feat + i);
        float4 b = *(const float4*)(feat + i + 4);
        short8 t;
        t[0] = f2bf(a.x); t[1] = f2bf(a.y); t[2] = f2bf(a.z); t[3] = f2bf(a.w);
        t[4] = f2bf(b.x); t[5] = f2bf(b.y); t[6] = f2bf(b.z); t[7] = f2bf(b.w);
        *(short8*)(featbf + i) = t;
    } else {
        int idx = (blk - basePrep) * 256 + threadIdx.x;   // 0..8191
        int layer = idx >> 12;
        int fi = idx & 4095;
        int fragidx = fi >> 9;
        int lane = (fi >> 3) & 63;
        int jj = fi & 7;
        int ct = fragidx >> 1, kt = fragidx & 1;
        int k = kt * 32 + (lane >> 4) * 8 + jj;
        int j = ct * 16 + (lane & 15);
        const float* W = layer ? W2 : W1;
        wf[idx] = f2bf(W[k * DIM + j]);
    }
}

// ---------------- partition3: chunk-local LDS counting sort, block-private writes ----------------
// Block c sorts its CHUNK edges by bucket in LDS, dumps contiguously to
// edgebuf[c*CHUNK ..] and writes its exclusive-scan row offs_g[c][0..NB].
__global__ __launch_bounds__(512) void partition3(const int* __restrict__ src,
                                                  const int* __restrict__ dst,
                                                  int* __restrict__ offs_g,
                                                  int* __restrict__ edgebuf) {
    __shared__ int cnt[NB];
    __shared__ int lcur[NB];
    __shared__ int partial[512];
    __shared__ int estage[CHUNK];

    int c = blockIdx.x;
    int t = threadIdx.x;
    int base = c * CHUNK;
    int end = base + CHUNK; if (end > N_EDGES) end = N_EDGES;

    for (int b = t; b < NB; b += 512) cnt[b] = 0;
    __syncthreads();
    for (int i = base + t; i < end; i += 512)
        atomicAdd(&cnt[dst[i] >> 7], 1);
    __syncthreads();

    // exclusive scan over NB buckets: thread t owns buckets 2t, 2t+1
    int b0 = 2 * t, b1 = 2 * t + 1;
    int v0 = (b0 < NB) ? cnt[b0] : 0;
    int v1 = (b1 < NB) ? cnt[b1] : 0;
    partial[t] = v0 + v1;
    __syncthreads();
    for (int off = 1; off < 512; off <<= 1) {
        int u = (t >= off) ? partial[t - off] : 0;
        __syncthreads();
        partial[t] += u;
        __syncthreads();
    }
    int ex = partial[t] - (v0 + v1);
    int* orow = offs_g + (size_t)c * (NB + 1);
    if (b0 < NB) { lcur[b0] = ex;      orow[b0] = ex; }
    if (b1 < NB) { lcur[b1] = ex + v0; orow[b1] = ex + v0; }
    if (t == 511) orow[NB] = partial[511];    // total edges in chunk
    __syncthreads();

    // place into LDS staging grouped by bucket (LDS return-atomics)
    for (int i = base + t; i < end; i += 512) {
        int d = dst[i];
        int p = atomicAdd(&lcur[d >> 7], 1);
        estage[p] = src[i] | ((d & 127) << 17);
    }
    __syncthreads();

    // contiguous, block-private, full-line dump
    int n = end - base;
    for (int i = t; i < n; i += 512) edgebuf[base + i] = estage[i];
}

// ---------------- fused gather + combine + 2-layer MLP ----------------
// Bucket b's edges live in 512 chunk-local segments:
// edgebuf[c*CHUNK + offs_g[c][b] .. c*CHUNK + offs_g[c][b+1])
template<int BF>
__global__ __launch_bounds__(512) void fused_gather_mlp(const int* __restrict__ offs_g,
                                                        const int* __restrict__ edgebuf,
                                                        const void* __restrict__ featp,
                                                        const float* __restrict__ feat,
                                                        const short* __restrict__ wf,
                                                        const float* __restrict__ b1,
                                                        const float* __restrict__ b2,
                                                        const float* __restrict__ epsp,
                                                        float* __restrict__ out) {
    __shared__ union {
        struct { int ew[MAXE]; int es[MAXE]; } s;   // 32 KB sort phase
        float tile[128][66];                        // 33792 B neigh tile / hbuf
    } u;
    __shared__ int cnt[128], offs[128], cur[128];
    __shared__ int slen[NCHUNK], dloc[NCHUNK];
    __shared__ int sh_ec;

    int b = blockIdx.x;
    int node0 = b << 7;
    int tid = threadIdx.x;
    int c = tid & 15;               // feature chunk (4 floats)
    int slot = tid >> 4;            // 0..31

    // ---- phase 0: segment table for this bucket (scattered column reads) ----
    const int* row = offs_g + (size_t)tid * (NB + 1);
    int s0 = row[b];
    int myslen = row[b + 1] - s0;
    dloc[tid] = myslen;
    __syncthreads();
    for (int off = 1; off < 512; off <<= 1) {
        int v = (tid >= off) ? dloc[tid - off] : 0;
        __syncthreads();
        dloc[tid] += v;
        __syncthreads();
    }
    int incl = dloc[tid];
    __syncthreads();
    dloc[tid] = incl - myslen;      // exclusive
    slen[tid] = myslen;
    if (tid == 511) sh_ec = incl;
    __syncthreads();
    int ec = sh_ec;

    float acc[4][4];
#pragma unroll
    for (int g = 0; g < 4; ++g)
#pragma unroll
        for (int j = 0; j < 4; ++j) acc[g][j] = 0.f;

    // ---- phase 1: rounds of {copy segments -> ew, counting sort, accumulate} ----
    int c0 = 0;
    while (c0 < NCHUNK) {
        int rbase = dloc[c0];
        int pred = (tid >= c0) && (dloc[tid] + slen[tid] - rbase <= MAXE);
        int nc = __syncthreads_count(pred);
        int c1 = c0 + nc;

        if (tid < 128) cnt[tid] = 0;
        if (tid >= c0 && tid < c1 && myslen > 0) {
            int d0 = dloc[tid] - rbase;
            const int* sp = edgebuf + (size_t)tid * CHUNK + s0;
            for (int i = 0; i < myslen; ++i) u.s.ew[d0 + i] = sp[i];
        }
        __syncthreads();

        int n = ((c1 < NCHUNK) ? dloc[c1] : ec) - rbase;

        // per-node counts
        for (int i = tid; i < n; i += 512)
            atomicAdd(&cnt[(u.s.ew[i] >> 17) & 127], 1);
        __syncthreads();

        // exclusive scan of cnt[128]
        if (tid < 128) offs[tid] = cnt[tid];
        __syncthreads();
        for (int d = 1; d < 128; d <<= 1) {
            int v = 0;
            if (tid < 128 && tid >= d) v = offs[tid - d];
            __syncthreads();
            if (tid < 128 && tid >= d) offs[tid] += v;
            __syncthreads();
        }
        if (tid < 128) {
            int x = offs[tid] - cnt[tid];
            offs[tid] = x;
            cur[tid] = x;
        }
        __syncthreads();

        // place grouped by local dst
        for (int i = tid; i < n; i += 512) {
            int w = u.s.ew[i];
            int p = atomicAdd(&cur[(w >> 17) & 127], 1);
            u.s.es[p] = w & 0x1FFFF;
        }
        __syncthreads();

        // segmented register gather
#pragma unroll
        for (int g = 0; g < 4; ++g) {
            int ld = g * 32 + slot;
            int e0 = offs[ld], e1 = e0 + cnt[ld];
            int i = e0;
            for (; i + 1 < e1; i += 2) {
                int sa = u.s.es[i], sb = u.s.es[i + 1];
                if (BF) {
                    uint2 pa = ((const uint2*)featp)[sa * 16 + c];
                    uint2 pb = ((const uint2*)featp)[sb * 16 + c];
                    acc[g][0] += bfu2f(pa.x & 0xffffu) + bfu2f(pb.x & 0xffffu);
                    acc[g][1] += bfu2f(pa.x >> 16)     + bfu2f(pb.x >> 16);
                    acc[g][2] += bfu2f(pa.y & 0xffffu) + bfu2f(pb.y & 0xffffu);
                    acc[g][3] += bfu2f(pa.y >> 16)     + bfu2f(pb.y >> 16);
                } else {
                    float4 va = ((const float4*)featp)[sa * 16 + c];
                    float4 vb = ((const float4*)featp)[sb * 16 + c];
                    acc[g][0] += va.x + vb.x;
                    acc[g][1] += va.y + vb.y;
                    acc[g][2] += va.z + vb.z;
                    acc[g][3] += va.w + vb.w;
                }
            }
            if (i < e1) {
                int sa = u.s.es[i];
                if (BF) {
                    uint2 pa = ((const uint2*)featp)[sa * 16 + c];
                    acc[g][0] += bfu2f(pa.x & 0xffffu);
                    acc[g][1] += bfu2f(pa.x >> 16);
                    acc[g][2] += bfu2f(pa.y & 0xffffu);
                    acc[g][3] += bfu2f(pa.y >> 16);
                } else {
                    float4 va = ((const float4*)featp)[sa * 16 + c];
                    acc[g][0] += va.x; acc[g][1] += va.y;
                    acc[g][2] += va.z; acc[g][3] += va.w;
                }
            }
        }
        __syncthreads();    // ew/es reused next round (or tile after loop)
        c0 = c1;
    }

    // ---- phase 2: neigh -> LDS tile (stride 66) ----
#pragma unroll
    for (int g = 0; g < 4; ++g) {
        int ld = g * 32 + slot;
#pragma unroll
        for (int j = 0; j < 4; ++j)
            u.tile[ld][c * 4 + j] = acc[g][j];
    }
    __syncthreads();

    // ---- phase 3: MLP, one wave per 16 rows ----
    int wv = tid >> 6;
    int lane = tid & 63;
    int r = lane & 15, gg = lane >> 4;
    int lrow = wv * 16 + r;             // local row 0..127
    int node = node0 + lrow;
    bool valid = node < N_NODES;
    float epsv = 1.0f + epsp[0];

    const short8* w1f8 = (const short8*)(wf);
    const short8* w2f8 = (const short8*)(wf + 4096);

    short8 a[2];
    {
        const float* fp = feat + (size_t)node * 64 + gg * 8;
#pragma unroll
        for (int kt = 0; kt < 2; ++kt) {
            float f0x=0,f0y=0,f0z=0,f0w=0,f1x=0,f1y=0,f1z=0,f1w=0;
            if (valid) {
                float4 f0 = *(const float4*)(fp + kt * 32);
                float4 f1 = *(const float4*)(fp + kt * 32 + 4);
                f0x=f0.x; f0y=f0.y; f0z=f0.z; f0w=f0.w;
                f1x=f1.x; f1y=f1.y; f1z=f1.z; f1w=f1.w;
            }
            const float2* tp = (const float2*)&u.tile[lrow][kt * 32 + gg * 8];
            float2 n0 = tp[0], n1 = tp[1], n2 = tp[2], n3 = tp[3];
            float rs[8] = { epsv * f0x + n0.x, epsv * f0y + n0.y,
                            epsv * f0z + n1.x, epsv * f0w + n1.y,
                            epsv * f1x + n2.x, epsv * f1y + n2.y,
                            epsv * f1z + n3.x, epsv * f1w + n3.y };
            short8 t;
#pragma unroll
            for (int jj = 0; jj < 8; ++jj) t[jj] = f2bf(rs[jj]);
            a[kt] = t;
        }
    }
    __syncthreads();    // all tile reads done before hbuf overwrite

    f32x4 acc1[4];
#pragma unroll
    for (int ct = 0; ct < 4; ++ct) {
        float bv = b1[ct * 16 + r];
        f32x4 cc = { bv, bv, bv, bv };
        cc = __builtin_amdgcn_mfma_f32_16x16x32_bf16(
                __builtin_bit_cast(bf16x8, a[0]),
                __builtin_bit_cast(bf16x8, w1f8[(ct * 2 + 0) * 64 + lane]),
                cc, 0, 0, 0);
        cc = __builtin_amdgcn_mfma_f32_16x16x32_bf16(
                __builtin_bit_cast(bf16x8, a[1]),
                __builtin_bit_cast(bf16x8, w1f8[(ct * 2 + 1) * 64 + lane]),
                cc, 0, 0, 0);
        acc1[ct] = cc;
    }

    // relu + transpose h through LDS (per-wave slice of tile)
#pragma unroll
    for (int ct = 0; ct < 4; ++ct)
#pragma unroll
        for (int i = 0; i < 4; ++i)
            u.tile[wv * 16 + gg * 4 + i][ct * 16 + r] = fmaxf(acc1[ct][i], 0.0f);
    __syncthreads();

    short8 a2[2];
#pragma unroll
    for (int kt = 0; kt < 2; ++kt) {
        const float2* hp = (const float2*)&u.tile[wv * 16 + r][kt * 32 + gg * 8];
        float2 h0 = hp[0], h1 = hp[1], h2 = hp[2], h3 = hp[3];
        float hs[8] = { h0.x, h0.y, h1.x, h1.y, h2.x, h2.y, h3.x, h3.y };
        short8 t;
#pragma unroll
        for (int jj = 0; jj < 8; ++jj) t[jj] = f2bf(hs[jj]);
        a2[kt] = t;
    }

    f32x4 acc2[4];
#pragma unroll
    for (int ct = 0; ct < 4; ++ct) {
        float bv = b2[ct * 16 + r];
        f32x4 cc = { bv, bv, bv, bv };
        cc = __builtin_amdgcn_mfma_f32_16x16x32_bf16(
                __builtin_bit_cast(bf16x8, a2[0]),
                __builtin_bit_cast(bf16x8, w2f8[(ct * 2 + 0) * 64 + lane]),
                cc, 0, 0, 0);
        cc = __builtin_amdgcn_mfma_f32_16x16x32_bf16(
                __builtin_bit_cast(bf16x8, a2[1]),
                __builtin_bit_cast(bf16x8, w2f8[(ct * 2 + 1) * 64 + lane]),
                cc, 0, 0, 0);
        acc2[ct] = cc;
    }

#pragma unroll
    for (int ct = 0; ct < 4; ++ct)
#pragma unroll
        for (int i = 0; i < 4; ++i) {
            int nrow = node0 + wv * 16 + gg * 4 + i;
            if (nrow < N_NODES)
                out[(size_t)nrow * 64 + ct * 16 + r] = acc2[ct][i];
        }
}

// ---------------- tiny-ws fallback: atomic scatter + separate MLP ----------------
__global__ __launch_bounds__(256) void scatter_edges(const float4* __restrict__ feat4,
                                                     const int* __restrict__ src,
                                                     const int* __restrict__ dst,
                                                     float* __restrict__ neigh) {
    int idx = blockIdx.x * 256 + threadIdx.x;
    int e = idx >> 4, c = idx & 15;
    int s = src[e], d = dst[e];
    float4 v = feat4[s * 16 + c];
    float* p = neigh + d * 64 + c * 4;
    unsafeAtomicAdd(p + 0, v.x);
    unsafeAtomicAdd(p + 1, v.y);
    unsafeAtomicAdd(p + 2, v.z);
    unsafeAtomicAdd(p + 3, v.w);
}

__global__ __launch_bounds__(256) void prep_w(const float* __restrict__ W1,
                                              const float* __restrict__ W2,
                                              short* __restrict__ wf) {
    int idx = blockIdx.x * 256 + threadIdx.x;
    int layer = idx >> 12;
    int fi = idx & 4095;
    int fragidx = fi >> 9;
    int lane = (fi >> 3) & 63;
    int jj = fi & 7;
    int ct = fragidx >> 1, kt = fragidx & 1;
    int k = kt * 32 + (lane >> 4) * 8 + jj;
    int j = ct * 16 + (lane & 15);
    const float* W = layer ? W2 : W1;
    wf[idx] = f2bf(W[k * DIM + j]);
}

__global__ __launch_bounds__(256) void gin_mlp(const float* __restrict__ feat,
                                               float* __restrict__ neigh_out,
                                               const short* __restrict__ wf,
                                               const float* __restrict__ b1,
                                               const float* __restrict__ b2,
                                               const float* __restrict__ epsp) {
    __shared__ float hbuf[4][16][66];
    int lane = threadIdx.x & 63;
    int wv = threadIdx.x >> 6;
    int r = lane & 15, g = lane >> 4;
    int row0 = blockIdx.x * 64 + wv * 16;
    int node = row0 + r;
    bool valid = node < N_NODES;
    float epsv = 1.0f + epsp[0];
    const short8* w1f8 = (const short8*)(wf);
    const short8* w2f8 = (const short8*)(wf + 4096);
    short8 a[2];
    if (valid) {
        const float* fp = feat + node * 64 + g * 8;
        const float* np_ = neigh_out + node * 64 + g * 8;
#pragma unroll
        for (int kt = 0; kt < 2; ++kt) {
            float4 f0 = *(const float4*)(fp + kt * 32);
            float4 f1 = *(const float4*)(fp + kt * 32 + 4);
            float4 n0 = *(const float4*)(np_ + kt * 32);
            float4 n1 = *(const float4*)(np_ + kt * 32 + 4);
            float rs[8] = { epsv * f0.x + n0.x, epsv * f0.y + n0.y,
                            epsv * f0.z + n0.z, epsv * f0.w + n0.w,
                            epsv * f1.x + n1.x, epsv * f1.y + n1.y,
                            epsv * f1.z + n1.z, epsv * f1.w + n1.w };
            short8 t;
#pragma unroll
            for (int jj = 0; jj < 8; ++jj) t[jj] = f2bf(rs[jj]);
            a[kt] = t;
        }
    } else {
        short8 z = { 0,0,0,0,0,0,0,0 };
        a[0] = z; a[1] = z;
    }
    f32x4 acc[4];
#pragma unroll
    for (int ct = 0; ct < 4; ++ct) {
        float bv = b1[ct * 16 + r];
        f32x4 c = { bv, bv, bv, bv };
        c = __builtin_amdgcn_mfma_f32_16x16x32_bf16(
                __builtin_bit_cast(bf16x8, a[0]),
                __builtin_bit_cast(bf16x8, w1f8[(ct * 2 + 0) * 64 + lane]), c, 0, 0, 0);
        c = __builtin_amdgcn_mfma_f32_16x16x32_bf16(
                __builtin_bit_cast(bf16x8, a[1]),
                __builtin_bit_cast(bf16x8, w1f8[(ct * 2 + 1) * 64 + lane]), c, 0, 0, 0);
        acc[ct] = c;
    }
#pragma unroll
    for (int ct = 0; ct < 4; ++ct)
#pragma unroll
        for (int i = 0; i < 4; ++i)
            hbuf[wv][g * 4 + i][ct * 16 + r] = fmaxf(acc[ct][i], 0.0f);
    __syncthreads();
    short8 a2[2];
#pragma unroll
    for (int kt = 0; kt < 2; ++kt) {
        const float2* hp = (const float2*)&hbuf[wv][r][kt * 32 + g * 8];
        float2 h0 = hp[0], h1 = hp[1], h2 = hp[2], h3 = hp[3];
        float hs[8] = { h0.x, h0.y, h1.x, h1.y, h2.x, h2.y, h3.x, h3.y };
        short8 t;
#pragma unroll
        for (int jj = 0; jj < 8; ++jj) t[jj] = f2bf(hs[jj]);
        a2[kt] = t;
    }
    f32x4 acc2[4];
#pragma unroll
    for (int ct = 0; ct < 4; ++ct) {
        float bv = b2[ct * 16 + r];
        f32x4 c = { bv, bv, bv, bv };
        c = __builtin_amdgcn_mfma_f32_16x16x32_bf16(
                __builtin_bit_cast(bf16x8, a2[0]),
                __builtin_bit_cast(bf16x8, w2f8[(ct * 2 + 0) * 64 + lane]), c, 0, 0, 0);
        c = __builtin_amdgcn_mfma_f32_16x16x32_bf16(
                __builtin_bit_cast(bf16x8, a2[1]),
                __builtin_bit_cast(bf16x8, w2f8[(ct * 2 + 1) * 64 + lane]), c, 0, 0, 0);
        acc2[ct] = c;
    }
#pragma unroll
    for (int ct = 0; ct < 4; ++ct)
#pragma unroll
        for (int i = 0; i < 4; ++i) {
            int nrow = row0 + g * 4 + i;
            if (nrow < N_NODES)
                neigh_out[nrow * 64 + ct * 16 + r] = acc2[ct][i];
        }
}

extern "C" void kernel_launch(void* const* d_in, const int* in_sizes, int n_in,
                              void* d_out, int out_size, void* d_ws, size_t ws_size,
                              hipStream_t stream) {
    const float* feat = (const float*)d_in[0];
    const float* W1   = (const float*)d_in[1];
    const float* b1   = (const float*)d_in[2];
    const float* W2   = (const float*)d_in[3];
    const float* b2   = (const float*)d_in[4];
    const float* eps  = (const float*)d_in[5];
    const int*   src  = (const int*)d_in[6];
    const int*   dst  = (const int*)d_in[7];
    float* out = (float*)d_out;

    char* ws = (char*)d_ws;
    short* wf = (short*)ws;                                     // 16384 B

    const size_t featbf_bytes = (size_t)N_NODES * DIM * 2;      // 12.8 MB
    const size_t offs_bytes   = (size_t)NCHUNK * (NB + 1) * 4;  // 1.6 MB
    const size_t edge_bytes   = (size_t)NCHUNK * CHUNK * 4;     // 5.0 MB
    const size_t need_mid  = 16384 + offs_bytes + edge_bytes;
    const size_t need_full = need_mid + featbf_bytes;

    if (ws_size >= need_mid) {
        char* p = ws + 16384;
        short* featbf = nullptr;
        if (ws_size >= need_full) { featbf = (short*)p; p += featbf_bytes; }
        int* offs_g  = (int*)p;            p += offs_bytes;
        int* edgebuf = (int*)p;

        int basePrep = featbf ? 3125 : 0;       // 6.4M floats / (256*8)
        prologue<<<basePrep + 32, 256, 0, stream>>>(feat, featbf, W1, W2, wf, basePrep);

        partition3<<<NCHUNK, 512, 0, stream>>>(src, dst, offs_g, edgebuf);

        if (featbf)
            fused_gather_mlp<1><<<NB, 512, 0, stream>>>(
                offs_g, edgebuf, featbf, feat, wf, b1, b2, eps, out);
        else
            fused_gather_mlp<0><<<NB, 512, 0, stream>>>(
                offs_g, edgebuf, feat, feat, wf, b1, b2, eps, out);
    } else {
        prep_w<<<32, 256, 0, stream>>>(W1, W2, wf);
        hipMemsetAsync(d_out, 0, (size_t)N_NODES * DIM * sizeof(float), stream);
        scatter_edges<<<(N_EDGES * 16) / 256, 256, 0, stream>>>(
            (const float4*)feat, src, dst, out);
        gin_mlp<<<(N_NODES + 63) / 64, 256, 0, stream>>>(feat, out, wf, b1, b2, eps);
    }
}